// Round 8
// baseline (6192.751 us; speedup 1.0000x reference)
//
#include <hip/hip_runtime.h>
#include <math.h>

#define TSTEPS 1000
#define NS 512
#define HD 512
#define MWG 16
#define NWG 32
#define NTHREADS 512
#define APITCH 520                 // a_lds row pitch (elems); 1040B rows
#define TSTRIDE (16*512)           // elems per tile in packed W (16 kbs)
#define ABUF (MWG*APITCH)          // elems per a buffer

typedef __attribute__((ext_vector_type(8))) short bf16x8;
typedef __attribute__((ext_vector_type(4))) float f32x4;

#define A_BYTES   (2*ABUF*2)                        // 33280 (double-buffered)
#define OP_BYTES  (2*8*MWG*2*4)                     // 2048  (double-buffered)
#define SMEM_BYTES (A_BYTES + OP_BYTES)             // 35328

#define MFMA_ __builtin_amdgcn_mfma_f32_16x16x32_bf16

__device__ __forceinline__ unsigned short f2bf(float f) {
    union { float f; unsigned u; } v; v.f = f;
    unsigned u = v.u + 0x7FFFu + ((v.u >> 16) & 1u);
    return (unsigned short)(u >> 16);
}

__device__ __forceinline__ unsigned pkbf(float lo, float hi) {
    unsigned r;
    asm("v_cvt_pk_bf16_f32 %0, %1, %2" : "=v"(r) : "v"(lo), "v"(hi));
    return r;
}

__device__ __forceinline__ float relu_tanh(float x) {
    float xc = fminf(x, 10.0f);
    float e  = __builtin_amdgcn_exp2f(xc * 2.8853900817779268f);
    float t  = (e - 1.0f) * __builtin_amdgcn_rcpf(e + 1.0f);
    return fmaxf(t, 0.0f);
}

__device__ __forceinline__ void barrier_lds() {
    asm volatile("s_waitcnt lgkmcnt(0)\n\ts_barrier" ::: "memory");
}

// round-2 permutation: permuted-k -> source hidden index
// k' = wv*64 + c*4 + jj  <->  col = wv*64 + jj*16 + c   (wave owns 4 tiles)
__device__ __forceinline__ int pi_inv(int k) {
    return (k & ~63) | ((k & 3) << 4) | ((k >> 2) & 15);
}

// ---------- pack 0.1*W_rec (pi-permuted rows) into MFMA-B frags, tiles 0..31, kb 0..15 ----------
__global__ void pack_w(const float* __restrict__ Wrec, unsigned short* __restrict__ Wp) {
    int tid = blockIdx.x * 512 + threadIdx.x;      // 32 tiles * 16 kb * 64 lanes = 32768
    if (tid >= 32768) return;
    int c  = tid & 15;
    int gg = (tid >> 4) & 3;
    int kb = (tid >> 6) & 15;
    int nt = tid >> 10;
    union { unsigned short s[8]; bf16x8 v; } buf;
#pragma unroll
    for (int b = 0; b < 8; ++b) {
        int k = kb * 32 + gg * 8 + b;
        buf.s[b] = f2bf(0.1f * Wrec[(size_t)pi_inv(k) * HD + nt * 16 + c]);
    }
    *(bf16x8*)(Wp + (size_t)tid * 8) = buf.v;
}

// ---------- tile 32: Wro = W_rec @ W_out (UNscaled, pi-permuted rows); extras = {Win@Wout, bias@Wout} ----------
__global__ void pack_wro(const float* __restrict__ Wrec, const float* __restrict__ Win,
                         const float* __restrict__ Wout, const float* __restrict__ bias,
                         unsigned short* __restrict__ Wp, float* __restrict__ extras) {
    __shared__ float wf[512][2];
    int tid = threadIdx.x;    // 512
    {
        int sr = pi_inv(tid);
        float s0 = 0.f, s1 = 0.f;
        for (int h = 0; h < HD; ++h) {
            float w = Wrec[(size_t)sr * HD + h];
            s0 += w * Wout[2 * h]; s1 += w * Wout[2 * h + 1];
        }
        wf[tid][0] = s0; wf[tid][1] = s1;
    }
    __syncthreads();
    for (int i = tid; i < 16 * 64; i += 512) {
        int lane = i & 63, kb = i >> 6, cc = lane & 15;
        union { unsigned short s[8]; bf16x8 v; } buf;
#pragma unroll
        for (int b = 0; b < 8; ++b) {
            int k = kb * 32 + (lane >> 4) * 8 + b;
            buf.s[b] = (cc < 2) ? f2bf(wf[k][cc]) : (unsigned short)0;
        }
        *(bf16x8*)(Wp + (size_t)32 * TSTRIDE + kb * 512 + lane * 8) = buf.v;
    }
    // extras[0..3] = Wio[di][d] (idx di*2+d), extras[4..5] = bo[d]  (UNscaled)
    if (tid < 6) {
        int d = tid & 1;
        float s = 0.f;
        if (tid < 4) {
            const float* src = Win + (tid >> 1) * HD;
            for (int h = 0; h < HD; ++h) s += src[h] * Wout[2 * h + d];
        } else {
            for (int h = 0; h < HD; ++h) s += bias[h] * Wout[2 * h + d];
        }
        extras[tid] = s;
    }
}

// ---------- persistent RNN: 8 waves; W: regs(kb0..3, pinned) + explicit 3-buf L2 stream(kb4..15) ----------
__global__ __launch_bounds__(NTHREADS, 2)
void rnn8s(const float* __restrict__ initdir, const float* __restrict__ vel,
           const float* __restrict__ fcw, const float* __restrict__ fcb,
           const float* __restrict__ W_in, const float* __restrict__ Wout,
           const float* __restrict__ bias,
           const unsigned short* __restrict__ Wp, const float* __restrict__ extras,
           float* __restrict__ out)
{
    extern __shared__ char smem[];
    unsigned short* a_lds = (unsigned short*)smem;                        // [2][16][520]
    float*          opart = (float*)(smem + A_BYTES);                     // [2][8][16][2]

    const int tid = threadIdx.x, lane = tid & 63, wv = tid >> 6;
    const int g = lane >> 4, c = lane & 15;
    const int i0 = blockIdx.x * MWG;

    // register-resident W: kbs 0..3, this wave's 4 tiles — pinned against remat
    bf16x8 wreg[4][4];
#pragma unroll
    for (int kk = 0; kk < 4; ++kk)
#pragma unroll
        for (int jj = 0; jj < 4; ++jj)
            wreg[kk][jj] = *(const bf16x8*)(Wp + (size_t)(wv * 4 + jj) * TSTRIDE + kk * 512 + lane * 8);
    bf16x8 wro[2];
#pragma unroll
    for (int s = 0; s < 2; ++s)
        wro[s] = *(const bf16x8*)(Wp + (size_t)32 * TSTRIDE + (2 * wv + s) * 512 + lane * 8);
#pragma unroll
    for (int kk = 0; kk < 4; ++kk)
#pragma unroll
        for (int jj = 0; jj < 4; ++jj)
            asm volatile("" : "+v"(wreg[kk][jj]));
    asm volatile("" : "+v"(wro[0]), "+v"(wro[1]));

    // per-lane invariants (0.1-prescaled input path); h0
    float win0[4], win1[4], bc[4];
    f32x4 acc[4];                      // holds 0.9*h between steps (MFMA C)
    float av0[4][4];
    float p0[4] = {0.f,0.f,0.f,0.f}, p1[4] = {0.f,0.f,0.f,0.f};
#pragma unroll
    for (int jj = 0; jj < 4; ++jj) {
        int col = (wv * 4 + jj) * 16 + c;
        win0[jj] = 0.1f * W_in[col];
        win1[jj] = 0.1f * W_in[HD + col];
        bc[jj]   = 0.1f * bias[col];
        float wo0 = Wout[2 * col], wo1 = Wout[2 * col + 1];
        float fw0 = fcw[2*col], fw1 = fcw[2*col+1], fb = fcb[col];
#pragma unroll
        for (int r = 0; r < 4; ++r) {
            int i = i0 + g * 4 + r;
            float h0 = initdir[2*i] * fw0 + initdir[2*i+1] * fw1 + fb;
            acc[jj][r] = 0.9f * h0;
            p0[r] += h0 * wo0; p1[r] += h0 * wo1;
            av0[jj][r] = relu_tanh(h0);
        }
    }
#pragma unroll
    for (int m = 1; m <= 8; m <<= 1)
#pragma unroll
        for (int r = 0; r < 4; ++r) {
            p0[r] += __shfl_xor(p0[r], m, 64);
            p1[r] += __shfl_xor(p1[r], m, 64);
        }

    __syncthreads();

    // write a_0 into buffer 0, o-partials(h0) into opart[0]
    {
        unsigned short* aw0 = a_lds + wv * 64 + 4 * c;
#pragma unroll
        for (int r = 0; r < 4; ++r) {
            uint2 v;
            v.x = pkbf(av0[0][r], av0[1][r]);
            v.y = pkbf(av0[2][r], av0[3][r]);
            *(uint2*)(aw0 + (g * 4 + r) * APITCH) = v;
        }
        if (c == 0) {
#pragma unroll
            for (int r = 0; r < 4; ++r) {
                opart[wv * 32 + (g * 4 + r) * 2 + 0] = p0[r];
                opart[wv * 32 + (g * 4 + r) * 2 + 1] = p1[r];
            }
        }
    }
    __syncthreads();

    // reducer state (tid<32): o_0 = h0 @ W_out
    const int rrow = tid >> 1, rd = tid & 1;
    float o_state = 0.f, wio_x = 0.f, wio_y = 0.f, bo_d = 0.f;
    float2 oxv = make_float2(0.f, 0.f);
    if (tid < 32) {
        float s = 0.f;
#pragma unroll
        for (int w = 0; w < 8; ++w) s += opart[w * 32 + rrow * 2 + rd];
        o_state = s;
        wio_x = extras[rd]; wio_y = extras[2 + rd]; bo_d = extras[4 + rd];
    }

    // x prefetch for t=0 (rows 4g..4g+3)
    f32x4 xa = *(const f32x4*)(vel + (size_t)(i0 + 4 * g) * 2);
    f32x4 xb = *(const f32x4*)(vel + (size_t)(i0 + 4 * g) * 2 + 4);

#define PH_REG(kb) do { bf16x8 af = *(const bf16x8*)(ab + (kb)*32); \
    _Pragma("unroll") for (int jj = 0; jj < 4; ++jj) acc[jj] = MFMA_(af, wreg[kb][jj], acc[jj], 0,0,0); } while(0)

#define LOAD2(S, kb) do { _Pragma("unroll") for (int jj = 0; jj < 4; ++jj) { \
    S[jj]   = *(const bf16x8*)(Wp + (size_t)(wv*4+jj) * TSTRIDE + (kb)*512 + lane*8); \
    S[4+jj] = *(const bf16x8*)(Wp + (size_t)(wv*4+jj) * TSTRIDE + ((kb)+1)*512 + lane*8); } } while(0)

#define PH_STR2(S, kb) do { \
    { bf16x8 af = *(const bf16x8*)(ab + (kb)*32); \
      _Pragma("unroll") for (int jj = 0; jj < 4; ++jj) acc[jj] = MFMA_(af, S[jj], acc[jj], 0,0,0); } \
    { bf16x8 af = *(const bf16x8*)(ab + ((kb)+1)*32); \
      _Pragma("unroll") for (int jj = 0; jj < 4; ++jj) acc[jj] = MFMA_(af, S[4+jj], acc[jj], 0,0,0); } } while(0)

    // prologue stream: 3 buffers, 2 kbs each
    bf16x8 s0[8], s1[8], s2[8];
    LOAD2(s0, 4); LOAD2(s1, 6); LOAD2(s2, 8);

#pragma unroll 1
    for (int t = 0; t < TSTEPS; ++t) {
        const int pb = t & 1;
        const unsigned short* ab = a_lds + pb * ABUF + c * APITCH + g * 8;
        unsigned short*       aw = a_lds + (pb ^ 1) * ABUF + wv * 64 + 4 * c;
        const float* opr = opart + pb * 256;
        float*       opw = opart + (pb ^ 1) * 256;

        // finish step t-1's output (overlaps other waves' MFMA phase)
        if (tid < 32) {
            if (t > 0) {
                float s = 0.f;
#pragma unroll
                for (int w = 0; w < 8; ++w) s += opr[w * 32 + rrow * 2 + rd];
                o_state = 0.9f * o_state + 0.1f * (s + oxv.x * wio_x + oxv.y * wio_y + bo_d);
                out[((size_t)(t - 1) * NS + i0 + rrow) * 2 + rd] = o_state;
            }
            oxv = *(const float2*)(vel + ((size_t)t * NS + i0 + rrow) * 2);   // for t+1
        }

        // main MFMA: kbs 0..3 from pinned regs (covers stream latency), 4..15 streamed
        PH_REG(0); PH_REG(1); PH_REG(2); PH_REG(3);
        PH_STR2(s0, 4);   LOAD2(s0, 10);
        PH_STR2(s1, 6);   LOAD2(s1, 12);
        PH_STR2(s2, 8);   LOAD2(s2, 14);
        PH_STR2(s0, 10);  LOAD2(s0, 4);    // reload for t+1
        PH_STR2(s1, 12);  LOAD2(s1, 6);    // reload for t+1
        PH_STR2(s2, 14);  LOAD2(s2, 8);    // reload for t+1

        // o-partials: this wave's 2 k-blocks against Wro
        f32x4 acco = {0.f, 0.f, 0.f, 0.f};
#pragma unroll
        for (int s = 0; s < 2; ++s) {
            bf16x8 af = *(const bf16x8*)(ab + (2 * wv + s) * 32);
            acco = MFMA_(af, wro[s], acco, 0, 0, 0);
        }

        // h update in f32 VALU: hn = acc + x0*win0' + x1*win1' + bc' ; acc <- 0.9*hn
        float x0[4] = {xa[0], xa[2], xb[0], xb[2]};
        float x1[4] = {xa[1], xa[3], xb[1], xb[3]};
        uint2 wval[4];
#pragma unroll
        for (int r = 0; r < 4; ++r) {
            float av[4];
#pragma unroll
            for (int jj = 0; jj < 4; ++jj) {
                float hn = acc[jj][r] + x0[r] * win0[jj] + x1[r] * win1[jj] + bc[jj];
                acc[jj][r] = 0.9f * hn;
                av[jj] = relu_tanh(hn);
            }
            wval[r].x = pkbf(av[0], av[1]);
            wval[r].y = pkbf(av[2], av[3]);
        }

        // x prefetch for t+1 (stays in flight across the barrier)
        {
            int tn = (t + 1 < TSTEPS) ? (t + 1) : t;
            xa = *(const f32x4*)(vel + ((size_t)tn * NS + i0 + 4 * g) * 2);
            xb = *(const f32x4*)(vel + ((size_t)tn * NS + i0 + 4 * g) * 2 + 4);
        }

        // write a_{t+1} + o-partials into the OTHER buffers
#pragma unroll
        for (int r = 0; r < 4; ++r)
            *(uint2*)(aw + (g * 4 + r) * APITCH) = wval[r];
        if (c < 2) {
#pragma unroll
            for (int r = 0; r < 4; ++r)
                opw[wv * 32 + (g * 4 + r) * 2 + c] = acco[r];
        }

        barrier_lds();   // single barrier per step (lgkm only; vmcnt stays in flight)
    }

    // epilogue: out[999]  (step 999 wrote opart[(TSTEPS&1)]; oxv = vel[999])
    if (tid < 32) {
        const float* opr = opart + (TSTEPS & 1) * 256;
        float s = 0.f;
#pragma unroll
        for (int w = 0; w < 8; ++w) s += opr[w * 32 + rrow * 2 + rd];
        o_state = 0.9f * o_state + 0.1f * (s + oxv.x * wio_x + oxv.y * wio_y + bo_d);
        out[((size_t)(TSTEPS - 1) * NS + i0 + rrow) * 2 + rd] = o_state;
    }
}

extern "C" void kernel_launch(void* const* d_in, const int* in_sizes, int n_in,
                              void* d_out, int out_size, void* d_ws, size_t ws_size,
                              hipStream_t stream) {
    (void)in_sizes; (void)n_in; (void)out_size; (void)ws_size;
    const float* initdir = (const float*)d_in[0];
    const float* vel     = (const float*)d_in[1];
    const float* fc_w    = (const float*)d_in[2];
    const float* fc_b    = (const float*)d_in[3];
    const float* W_in    = (const float*)d_in[4];
    const float* W_rec   = (const float*)d_in[5];
    const float* W_out   = (const float*)d_in[6];
    const float* bias    = (const float*)d_in[7];
    float* out           = (float*)d_out;

    unsigned short* Wp = (unsigned short*)d_ws;                             // 33 tiles * 16KB = 528KB
    float* extras      = (float*)((char*)d_ws + (size_t)33 * TSTRIDE * 2);  // 6 floats

    pack_w<<<64, 512, 0, stream>>>(W_rec, Wp);
    pack_wro<<<1, 512, 0, stream>>>(W_rec, W_in, W_out, bias, Wp, extras);

    hipFuncSetAttribute(reinterpret_cast<const void*>(&rnn8s),
                        hipFuncAttributeMaxDynamicSharedMemorySize, SMEM_BYTES);

    rnn8s<<<NWG, NTHREADS, SMEM_BYTES, stream>>>(
        initdir, vel, fc_w, fc_b, W_in, W_out, bias, Wp, extras, out);
}

// Round 9
// 2727.868 us; speedup vs baseline: 2.2702x; 2.2702x over previous
//
#include <hip/hip_runtime.h>
#include <math.h>

#define TSTEPS 1000
#define NS 512
#define HD 512
#define MWG 16
#define NWG 32
#define NTHREADS 512
#define APITCH 520                 // a_lds row pitch (elems); 1040B rows
#define TSTRIDE (16*512)           // elems per tile in packed W (16 kbs)

typedef __attribute__((ext_vector_type(8))) short bf16x8;
typedef __attribute__((ext_vector_type(4))) float f32x4;
typedef __attribute__((ext_vector_type(4))) unsigned int u32x4;

// LDS map
#define A_OFF    0
#define A_BYTES  (MWG*APITCH*2)            // 16640
#define OP_OFF   (A_OFF + A_BYTES)
#define OP_BYTES (8*MWG*2*4)               // 1024
#define WIN_OFF  (OP_OFF + OP_BYTES)
#define WIN_BYTES (3*512*4)                // 6144
#define WL_OFF   (WIN_OFF + WIN_BYTES)
#define WL_BYTES (32*4*512*2)              // 131072 (kb 9..12, 32 tiles)
#define SMEM_BYTES (WL_OFF + WL_BYTES)     // 154880

#define MFMA_ __builtin_amdgcn_mfma_f32_16x16x32_bf16

__device__ __forceinline__ unsigned short f2bf(float f) {
    union { float f; unsigned u; } v; v.f = f;
    unsigned u = v.u + 0x7FFFu + ((v.u >> 16) & 1u);
    return (unsigned short)(u >> 16);
}

__device__ __forceinline__ unsigned pkbf(float lo, float hi) {
    unsigned r;
    asm("v_cvt_pk_bf16_f32 %0, %1, %2" : "=v"(r) : "v"(lo), "v"(hi));
    return r;
}

__device__ __forceinline__ float relu_tanh(float x) {
    float xc = fminf(x, 10.0f);
    float e  = __builtin_amdgcn_exp2f(xc * 2.8853900817779268f);
    float t  = (e - 1.0f) * __builtin_amdgcn_rcpf(e + 1.0f);
    return fmaxf(t, 0.0f);
}

__device__ __forceinline__ void barrier_lds() {
    asm volatile("s_waitcnt lgkmcnt(0)\n\ts_barrier" ::: "memory");
}

// permuted-k -> source hidden index:  k' = wv*64 + c*4 + jj  <->  col = wv*64 + jj*16 + c
__device__ __forceinline__ int pi_inv(int k) {
    return (k & ~63) | ((k & 3) << 4) | ((k >> 2) & 15);
}
// col -> permuted k (inverse of pi_inv)
__device__ __forceinline__ int pi_col(int col) {
    return (col & ~63) | ((col & 15) << 2) | ((col >> 4) & 3);
}

// ---------- pack 0.1*W_rec (pi-permuted rows) into MFMA-B frags, tiles 0..31, kb 0..15 ----------
__global__ void pack_w(const float* __restrict__ Wrec, unsigned short* __restrict__ Wp) {
    int tid = blockIdx.x * 512 + threadIdx.x;      // 32 tiles * 16 kb * 64 lanes = 32768
    if (tid >= 32768) return;
    int c  = tid & 15;
    int gg = (tid >> 4) & 3;
    int kb = (tid >> 6) & 15;
    int nt = tid >> 10;
    union { unsigned short s[8]; bf16x8 v; } buf;
#pragma unroll
    for (int b = 0; b < 8; ++b) {
        int k = kb * 32 + gg * 8 + b;
        buf.s[b] = f2bf(0.1f * Wrec[(size_t)pi_inv(k) * HD + nt * 16 + c]);
    }
    *(bf16x8*)(Wp + (size_t)tid * 8) = buf.v;
}

// ---------- tile 32: Wro = W_rec @ W_out (UNscaled, pi rows); extras = {Win@Wout, bias@Wout} ----------
__global__ void pack_wro(const float* __restrict__ Wrec, const float* __restrict__ Win,
                         const float* __restrict__ Wout, const float* __restrict__ bias,
                         unsigned short* __restrict__ Wp, float* __restrict__ extras) {
    __shared__ float wf[512][2];
    int tid = threadIdx.x;    // 512
    {
        int sr = pi_inv(tid);
        float s0 = 0.f, s1 = 0.f;
        for (int h = 0; h < HD; ++h) {
            float w = Wrec[(size_t)sr * HD + h];
            s0 += w * Wout[2 * h]; s1 += w * Wout[2 * h + 1];
        }
        wf[tid][0] = s0; wf[tid][1] = s1;
    }
    __syncthreads();
    for (int i = tid; i < 16 * 64; i += 512) {
        int lane = i & 63, kb = i >> 6, cc = lane & 15;
        union { unsigned short s[8]; bf16x8 v; } buf;
#pragma unroll
        for (int b = 0; b < 8; ++b) {
            int k = kb * 32 + (lane >> 4) * 8 + b;
            buf.s[b] = (cc < 2) ? f2bf(wf[k][cc]) : (unsigned short)0;
        }
        *(bf16x8*)(Wp + (size_t)32 * TSTRIDE + kb * 512 + lane * 8) = buf.v;
    }
    if (tid < 6) {
        int d = tid & 1;
        float s = 0.f;
        if (tid < 4) {
            const float* src = Win + (tid >> 1) * HD;
            for (int h = 0; h < HD; ++h) s += src[h] * Wout[2 * h + d];
        } else {
            for (int h = 0; h < HD; ++h) s += bias[h] * Wout[2 * h + d];
        }
        extras[tid] = s;
    }
}

// ---------- persistent RNN: 8 waves; W: regs(kb0..8, pinned) + LDS(kb9..12) + asm-stream(kb13..15) ----------
__global__ __launch_bounds__(NTHREADS, 2)
void rnn9(const float* __restrict__ initdir, const float* __restrict__ vel,
          const float* __restrict__ fcw, const float* __restrict__ fcb,
          const float* __restrict__ W_in, const float* __restrict__ Wout,
          const float* __restrict__ bias,
          const unsigned short* __restrict__ Wp, const float* __restrict__ extras,
          float* __restrict__ out)
{
    extern __shared__ char smem[];
    unsigned short* a_lds   = (unsigned short*)(smem + A_OFF);     // [16][520]
    float*          opart   = (float*)(smem + OP_OFF);             // [8][16][2]
    float*          win_lds = (float*)(smem + WIN_OFF);            // [3][512] pi-ordered
    unsigned short* w_lds   = (unsigned short*)(smem + WL_OFF);    // [32*4][512]

    const int tid = threadIdx.x, lane = tid & 63, wv = tid >> 6;
    const int g = lane >> 4, c = lane & 15;
    const int i0 = blockIdx.x * MWG;

    // w_lds <- kbs 9..12 of all 32 tiles
    for (int i = tid; i < 8192; i += NTHREADS) {
        int ln = i & 63, b = i >> 6;            // b = tile*4 + (kb-9)
        int tile = b >> 2, kbr = b & 3;
        *(bf16x8*)(w_lds + b * 512 + ln * 8) =
            *(const bf16x8*)(Wp + (size_t)tile * TSTRIDE + (9 + kbr) * 512 + ln * 8);
    }
    // win_lds: 0.1*W_in rows + 0.1*bias in pi layout (f32x4 per lane per step)
    {
        int col = tid, p = pi_col(col);
        win_lds[p]        = 0.1f * W_in[col];
        win_lds[512 + p]  = 0.1f * W_in[HD + col];
        win_lds[1024 + p] = 0.1f * bias[col];
    }

    // register-resident W: kbs 0..8, this wave's 4 tiles — pinned against remat
    bf16x8 wreg[9][4];
#pragma unroll
    for (int kk = 0; kk < 9; ++kk)
#pragma unroll
        for (int jj = 0; jj < 4; ++jj)
            wreg[kk][jj] = *(const bf16x8*)(Wp + (size_t)(wv * 4 + jj) * TSTRIDE + kk * 512 + lane * 8);
    bf16x8 wro[2];
#pragma unroll
    for (int s = 0; s < 2; ++s)
        wro[s] = *(const bf16x8*)(Wp + (size_t)32 * TSTRIDE + (2 * wv + s) * 512 + lane * 8);
#pragma unroll
    for (int kk = 0; kk < 9; ++kk)
#pragma unroll
        for (int jj = 0; jj < 4; ++jj)
            asm volatile("" : "+v"(wreg[kk][jj]));
    asm volatile("" : "+v"(wro[0]), "+v"(wro[1]));

    // stream addressing: SRSRC over Wp; voffset = lane*16; soffset = tile*16KB + kb*1KB (wave-uniform)
    u32x4 srsrc;
    srsrc[0] = (unsigned)(unsigned long long)Wp;
    srsrc[1] = (unsigned)(((unsigned long long)Wp) >> 32);
    srsrc[2] = 0xFFFFFFFFu;
    srsrc[3] = 0x00020000u;
    const unsigned voff = lane * 16u;
    const int tb0 = __builtin_amdgcn_readfirstlane((wv * 4 + 0) * 16384);
    const int tb1 = __builtin_amdgcn_readfirstlane((wv * 4 + 1) * 16384);
    const int tb2 = __builtin_amdgcn_readfirstlane((wv * 4 + 2) * 16384);
    const int tb3 = __builtin_amdgcn_readfirstlane((wv * 4 + 3) * 16384);

#define ISSUE(Sa, Sb, Sc, Sd, kb) asm volatile( \
    "buffer_load_dwordx4 %0, %4, %5, %6 offen\n\t" \
    "buffer_load_dwordx4 %1, %4, %5, %7 offen\n\t" \
    "buffer_load_dwordx4 %2, %4, %5, %8 offen\n\t" \
    "buffer_load_dwordx4 %3, %4, %5, %9 offen" \
    : "=&v"(Sa), "=&v"(Sb), "=&v"(Sc), "=&v"(Sd) \
    : "v"(voff), "s"(srsrc), "s"(tb0 + (kb)*1024), "s"(tb1 + (kb)*1024), \
      "s"(tb2 + (kb)*1024), "s"(tb3 + (kb)*1024))

#define WAIT4 do { asm volatile("s_waitcnt vmcnt(4)"); __builtin_amdgcn_sched_barrier(0); } while(0)

    // per-lane h0 (acc seeded with 0.9*h0) + initial o-partials
    f32x4 acc[4];
    float av0[4][4];
    float p0[4] = {0.f,0.f,0.f,0.f}, p1[4] = {0.f,0.f,0.f,0.f};
#pragma unroll
    for (int jj = 0; jj < 4; ++jj) {
        int col = (wv * 4 + jj) * 16 + c;
        float wo0 = Wout[2 * col], wo1 = Wout[2 * col + 1];
        float fw0 = fcw[2*col], fw1 = fcw[2*col+1], fb = fcb[col];
#pragma unroll
        for (int r = 0; r < 4; ++r) {
            int i = i0 + g * 4 + r;
            float h0 = initdir[2*i] * fw0 + initdir[2*i+1] * fw1 + fb;
            acc[jj][r] = 0.9f * h0;
            p0[r] += h0 * wo0; p1[r] += h0 * wo1;
            av0[jj][r] = relu_tanh(h0);
        }
    }
#pragma unroll
    for (int m = 1; m <= 8; m <<= 1)
#pragma unroll
        for (int r = 0; r < 4; ++r) {
            p0[r] += __shfl_xor(p0[r], m, 64);
            p1[r] += __shfl_xor(p1[r], m, 64);
        }

    __syncthreads();   // w_lds + win_lds ready

    unsigned short* awr = a_lds + wv * 64 + 4 * c;
#pragma unroll
    for (int r = 0; r < 4; ++r) {
        uint2 v;
        v.x = pkbf(av0[0][r], av0[1][r]);
        v.y = pkbf(av0[2][r], av0[3][r]);
        *(uint2*)(awr + (g * 4 + r) * APITCH) = v;
    }
    if (c == 0) {
#pragma unroll
        for (int r = 0; r < 4; ++r) {
            opart[wv * 32 + (g * 4 + r) * 2 + 0] = p0[r];
            opart[wv * 32 + (g * 4 + r) * 2 + 1] = p1[r];
        }
    }
    __syncthreads();

    // reducer state (tid<32)
    const int rrow = tid >> 1, rd = tid & 1;
    float o_state = 0.f, wio_x = 0.f, wio_y = 0.f, bo_d = 0.f;
    float2 oxv = make_float2(0.f, 0.f);
    if (tid < 32) {
        float s = 0.f;
#pragma unroll
        for (int w = 0; w < 8; ++w) s += opart[w * 32 + rrow * 2 + rd];
        o_state = s;
        wio_x = extras[rd]; wio_y = extras[2 + rd]; bo_d = extras[4 + rd];
    }

    f32x4 xa = *(const f32x4*)(vel + (size_t)(i0 + 4 * g) * 2);
    f32x4 xb = *(const f32x4*)(vel + (size_t)(i0 + 4 * g) * 2 + 4);

    const unsigned short* ab = a_lds + c * APITCH + g * 8;

#define PH_REG(kb) do { bf16x8 af = *(const bf16x8*)(ab + (kb)*32); \
    _Pragma("unroll") for (int jj = 0; jj < 4; ++jj) acc[jj] = MFMA_(af, wreg[kb][jj], acc[jj], 0,0,0); } while(0)

#define PH_LDS(kb) do { bf16x8 af = *(const bf16x8*)(ab + (kb)*32); \
    _Pragma("unroll") for (int jj = 0; jj < 4; ++jj) { \
        bf16x8 wf = *(const bf16x8*)(w_lds + ((wv*4+jj)*4 + ((kb)-9)) * 512 + lane * 8); \
        acc[jj] = MFMA_(af, wf, acc[jj], 0,0,0); } } while(0)

#define PH_S(Sa, Sb, Sc, Sd, kb) do { bf16x8 af = *(const bf16x8*)(ab + (kb)*32); \
    acc[0] = MFMA_(af, Sa, acc[0],0,0,0); acc[1] = MFMA_(af, Sb, acc[1],0,0,0); \
    acc[2] = MFMA_(af, Sc, acc[2],0,0,0); acc[3] = MFMA_(af, Sd, acc[3],0,0,0); } while(0)

    // stream buffers + prologue issues (kb13, kb14)
    bf16x8 S13_0, S13_1, S13_2, S13_3;
    bf16x8 S14_0, S14_1, S14_2, S14_3;
    bf16x8 S15_0, S15_1, S15_2, S15_3;
    ISSUE(S13_0, S13_1, S13_2, S13_3, 13);
    ISSUE(S14_0, S14_1, S14_2, S14_3, 14);

#pragma unroll 1
    for (int t = 0; t < TSTEPS; ++t) {
        // finish step t-1's output (reads opart written post-barrier1 of t-1)
        if (tid < 32) {
            if (t > 0) {
                float s = 0.f;
#pragma unroll
                for (int w = 0; w < 8; ++w) s += opart[w * 32 + rrow * 2 + rd];
                o_state = 0.9f * o_state + 0.1f * (s + oxv.x * wio_x + oxv.y * wio_y + bo_d);
                out[((size_t)(t - 1) * NS + i0 + rrow) * 2 + rd] = o_state;
            }
            oxv = *(const float2*)(vel + ((size_t)t * NS + i0 + rrow) * 2);
        }

        PH_REG(0); PH_REG(1); PH_REG(2); PH_REG(3);
        WAIT4; PH_S(S13_0, S13_1, S13_2, S13_3, 13);
        ISSUE(S15_0, S15_1, S15_2, S15_3, 15);
        PH_REG(4); PH_REG(5); PH_REG(6); PH_REG(7); PH_REG(8);
        WAIT4; PH_S(S14_0, S14_1, S14_2, S14_3, 14);
        ISSUE(S13_0, S13_1, S13_2, S13_3, 13);          // for t+1
        PH_LDS(9); PH_LDS(10); PH_LDS(11); PH_LDS(12);
        WAIT4; PH_S(S15_0, S15_1, S15_2, S15_3, 15);
        ISSUE(S14_0, S14_1, S14_2, S14_3, 14);          // for t+1

        // o-partials: this wave's 2 k-blocks against Wro
        f32x4 acco = {0.f, 0.f, 0.f, 0.f};
#pragma unroll
        for (int s = 0; s < 2; ++s) {
            bf16x8 af = *(const bf16x8*)(ab + (2 * wv + s) * 32);
            acco = MFMA_(af, wro[s], acco, 0, 0, 0);
        }

        // h update: hn = acc + x0*win0' + x1*win1' + bc' ; acc <- 0.9*hn
        const f32x4 w0v = *(const f32x4*)(win_lds + wv * 64 + 4 * c);
        const f32x4 w1v = *(const f32x4*)(win_lds + 512 + wv * 64 + 4 * c);
        const f32x4 bcv = *(const f32x4*)(win_lds + 1024 + wv * 64 + 4 * c);
        float x0[4] = {xa[0], xa[2], xb[0], xb[2]};
        float x1[4] = {xa[1], xa[3], xb[1], xb[3]};
        uint2 wval[4];
#pragma unroll
        for (int r = 0; r < 4; ++r) {
            float av[4];
#pragma unroll
            for (int jj = 0; jj < 4; ++jj) {
                float hn = acc[jj][r] + x0[r] * w0v[jj] + x1[r] * w1v[jj] + bcv[jj];
                acc[jj][r] = 0.9f * hn;
                av[jj] = relu_tanh(hn);
            }
            wval[r].x = pkbf(av[0], av[1]);
            wval[r].y = pkbf(av[2], av[3]);
        }

        // x prefetch for t+1
        {
            int tn = (t + 1 < TSTEPS) ? (t + 1) : t;
            xa = *(const f32x4*)(vel + ((size_t)tn * NS + i0 + 4 * g) * 2);
            xb = *(const f32x4*)(vel + ((size_t)tn * NS + i0 + 4 * g) * 2 + 4);
        }

        barrier_lds();   // #1: all reads of a_t (+ writer's opart read) done

#pragma unroll
        for (int r = 0; r < 4; ++r)
            *(uint2*)(awr + (g * 4 + r) * APITCH) = wval[r];
        if (c < 2) {
#pragma unroll
            for (int r = 0; r < 4; ++r)
                opart[wv * 32 + (g * 4 + r) * 2 + c] = acco[r];
        }

        barrier_lds();   // #2: a_{t+1} + o-partials visible
    }

    asm volatile("s_waitcnt vmcnt(0)");   // drain stream before endpgm

    // epilogue: out[999]
    if (tid < 32) {
        float s = 0.f;
#pragma unroll
        for (int w = 0; w < 8; ++w) s += opart[w * 32 + rrow * 2 + rd];
        o_state = 0.9f * o_state + 0.1f * (s + oxv.x * wio_x + oxv.y * wio_y + bo_d);
        out[((size_t)(TSTEPS - 1) * NS + i0 + rrow) * 2 + rd] = o_state;
    }
}

extern "C" void kernel_launch(void* const* d_in, const int* in_sizes, int n_in,
                              void* d_out, int out_size, void* d_ws, size_t ws_size,
                              hipStream_t stream) {
    (void)in_sizes; (void)n_in; (void)out_size; (void)ws_size;
    const float* initdir = (const float*)d_in[0];
    const float* vel     = (const float*)d_in[1];
    const float* fc_w    = (const float*)d_in[2];
    const float* fc_b    = (const float*)d_in[3];
    const float* W_in    = (const float*)d_in[4];
    const float* W_rec   = (const float*)d_in[5];
    const float* W_out   = (const float*)d_in[6];
    const float* bias    = (const float*)d_in[7];
    float* out           = (float*)d_out;

    unsigned short* Wp = (unsigned short*)d_ws;                             // 33 tiles * 16KB
    float* extras      = (float*)((char*)d_ws + (size_t)33 * TSTRIDE * 2);  // 6 floats

    pack_w<<<64, 512, 0, stream>>>(W_rec, Wp);
    pack_wro<<<1, 512, 0, stream>>>(W_rec, W_in, W_out, bias, Wp, extras);

    hipFuncSetAttribute(reinterpret_cast<const void*>(&rnn9),
                        hipFuncAttributeMaxDynamicSharedMemorySize, SMEM_BYTES);

    rnn9<<<NWG, NTHREADS, SMEM_BYTES, stream>>>(
        initdir, vel, fc_w, fc_b, W_in, W_out, bias, Wp, extras, out);
}